// Round 10
// baseline (1557.629 us; speedup 1.0000x reference)
//
#include <hip/hip_runtime.h>
#include <hip/hip_bf16.h>

#define TPB 256

// ================= masks =================
__global__ __launch_bounds__(TPB) void k_mask0(const float* __restrict__ mask,
                                               float* __restrict__ m0, int n) {
  int i = blockIdx.x * TPB + threadIdx.x;
  if (i < n) m0[i] = (mask[i] < 0.1f) ? 1.0f : 0.0f;
}

__global__ __launch_bounds__(TPB) void k_downmask(const float* __restrict__ mi,
                                                  float* __restrict__ mo, int Dout) {
  int n = Dout * Dout * Dout;
  int idx = blockIdx.x * TPB + threadIdx.x;
  if (idx >= n) return;
  int Din = Dout * 2;
  int ox = idx % Dout, oy = (idx / Dout) % Dout, oz = idx / (Dout * Dout);
  float v = 0.f;
  for (int kz = 0; kz < 3; kz++) {
    int iz = 2 * oz + kz - 1; if ((unsigned)iz >= (unsigned)Din) continue;
    for (int ky = 0; ky < 3; ky++) {
      int iy = 2 * oy + ky - 1; if ((unsigned)iy >= (unsigned)Din) continue;
      for (int kx = 0; kx < 3; kx++) {
        int ix = 2 * ox + kx - 1; if ((unsigned)ix >= (unsigned)Din) continue;
        v = fmaxf(v, mi[(iz * Din + iy) * Din + ix]);
      }
    }
  }
  mo[idx] = v;
}

__global__ __launch_bounds__(TPB) void k_maskx(const float* __restrict__ x,
                                               const float* __restrict__ m,
                                               float* __restrict__ o,
                                               long total, int vox) {
  long i = blockIdx.x * (long)TPB + threadIdx.x;
  if (i < total) o[i] = x[i] * m[i % vox];
}

__global__ __launch_bounds__(TPB) void k_sumparts(const float* __restrict__ parts,
                                                  float* __restrict__ out,
                                                  long n, int s) {
  long i = blockIdx.x * (long)TPB + threadIdx.x;
  if (i >= n) return;
  float a = 0.f;
  for (int j = 0; j < s; j++) a += parts[(long)j * n + i];
  out[i] = a;
}

__global__ __launch_bounds__(TPB) void k_sumscat(const float* __restrict__ parts,
                                                 float* __restrict__ out,
                                                 int M, int Np, int Z, int Dh,
                                                 int lgDh, int cls) {
  long i = blockIdx.x * (long)TPB + threadIdx.x;
  long tot = (long)M * Np;
  if (i >= tot) return;
  int co = (int)(i >> (3 * lgDh));
  int pp = (int)(i & (Np - 1));
  float s = 0.f;
  for (int z = 0; z < Z; z++) s += parts[((long)z * M + co) * Np + pp];
  int px = cls & 1, py = (cls >> 1) & 1, pz = (cls >> 2) & 1;
  int ox = pp & (Dh - 1), oy = (pp >> lgDh) & (Dh - 1), oz = pp >> (2 * lgDh);
  int DF = Dh * 2;
  long fc = ((long)(2 * oz + pz) * DF + (2 * oy + py)) * DF + (2 * ox + px);
  out[(long)co * ((long)DF * DF * DF) + fc] = s;
}

// ================= tiled implicit-GEMM, split-K, reg-prefetch =================
// C[M][N] = A[M][K] x B[K][N]
// MODE 0: conv k3 s2 p1   MODE 2: 1x1 concat-fuse   MODE 3: conv k3 s1 p1
// MODE 4: convT parity class (C1 = pz<<2|py<<1|px)
// B-gather: per-lane laneOff + 27-bit validity mask; k-decode is wave-uniform.
template<int MT, int MODE>
__global__ __launch_bounds__(TPB) void k_gemm(const float* __restrict__ A,
                                              const float* __restrict__ B1,
                                              const float* __restrict__ B2,
                                              float* __restrict__ C,
                                              int M, int N, int K,
                                              int Din, int Dout, int C1,
                                              int kcPer) {
  constexpr int MR = MT / 16;
  constexpr int AEL = (MT == 64) ? 8 : 2;
  __shared__ __align__(16) float At[32][MT + 4];   // +4 pad: kills staging bank conflicts
  __shared__ __align__(16) float Bt[32][64];

  const int t = threadIdx.x;
  const int n0 = blockIdx.x * 64;
  const int m0 = blockIdx.y * MT;

  const int p0 = (t & 15) * 4;
  const int co0 = (t >> 4) * MR;

  const int pb = t & 63;
  const int kb0 = (t >> 6) * 8;       // wave-uniform
  const int pp = n0 + pb;
  const int oxb = pp & (Dout - 1);
  const int oyb = (pp / Dout) & (Dout - 1);
  const int ozb = pp / (Dout * Dout);

  int px = 0, py = 0, pz = 0, lgnx = 0, lgny = 0, lgT = 0, Cin = 0;
  if (MODE == 4) {
    px = C1 & 1; py = (C1 >> 1) & 1; pz = (C1 >> 2) & 1;
    lgnx = 1 - px; lgny = 1 - py;
    lgT = lgnx + lgny + (1 - pz);
    Cin = K >> lgT;
  }
  const long vin = (long)Din * Din * Din;

  // ---- per-lane gather precompute: laneOff + validity bitmask ----
  long laneOff = 0;
  unsigned vmask = 0;
  if (MODE == 0 || MODE == 3) {
    int bz = (MODE == 0 ? 2 * ozb : ozb) - 1;
    int by = (MODE == 0 ? 2 * oyb : oyb) - 1;
    int bx = (MODE == 0 ? 2 * oxb : oxb) - 1;
    laneOff = (long)bz * Din * Din + (long)by * Din + bx;
    if (pp < N) {
      for (int kz = 0; kz < 3; kz++)
        for (int ky = 0; ky < 3; ky++)
          for (int kx = 0; kx < 3; kx++) {
            bool ok = (unsigned)(bz + kz) < (unsigned)Din &&
                      (unsigned)(by + ky) < (unsigned)Din &&
                      (unsigned)(bx + kx) < (unsigned)Din;
            if (ok) vmask |= 1u << ((kz * 3 + ky) * 3 + kx);
          }
    }
  } else if (MODE == 4) {
    int bz = ozb - 1 + pz, by = oyb - 1 + py, bx = oxb - 1 + px;
    laneOff = (long)bz * Din * Din + (long)by * Din + bx;
    if (pp < N) {
      int nz_ = pz ? 1 : 2, ny_ = py ? 1 : 2, nx_ = px ? 1 : 2;
      for (int tz = 0; tz < nz_; tz++)
        for (int ty = 0; ty < ny_; ty++)
          for (int tx = 0; tx < nx_; tx++) {
            bool ok = (unsigned)(bz + tz) < (unsigned)Din &&
                      (unsigned)(by + ty) < (unsigned)Din &&
                      (unsigned)(bx + tx) < (unsigned)Din;
            if (ok) vmask |= 1u << ((tz << (lgny + lgnx)) | (ty << lgnx) | tx);
          }
    }
  }

  const int nch = (K + 31) >> 5;
  const int c0 = blockIdx.z * kcPer;
  int c1 = c0 + kcPer; if (c1 > nch) c1 = nch;

  float acc[MR][4];
#pragma unroll
  for (int a = 0; a < MR; a++)
#pragma unroll
    for (int b = 0; b < 4; b++) acc[a][b] = 0.f;

  float raf[AEL];
  float rb[8];
  const int co_a = (MT == 64) ? (t >> 2) : (t & 15);
  const int ka   = (MT == 64) ? ((t & 3) * 8) : ((t >> 4) * 2);
  const long arow = (long)(m0 + co_a) * K;

  auto loadA = [&](int c) {
    const int k0 = c << 5;
    if (MODE == 4) {
#pragma unroll
      for (int j = 0; j < AEL; j++) {
        const int kg = k0 + ka + j;
        float v = 0.f;
        if (kg < K) {
          int ci = kg >> lgT;
          int tt = kg & ((1 << lgT) - 1);
          int tx = tt & ((1 << lgnx) - 1); tt >>= lgnx;
          int ty = tt & ((1 << lgny) - 1);
          int tz = tt >> lgny;
          int kx = px ? 1 : (tx << 1);
          int ky = py ? 1 : (ty << 1);
          int kz = pz ? 1 : (tz << 1);
          v = A[((long)(m0 + co_a) * Cin + ci) * 27 + (kz * 3 + ky) * 3 + kx];
        }
        raf[j] = v;
      }
    } else if (MT == 64) {
#pragma unroll
      for (int j = 0; j < 2; j++) {
        const int kg = k0 + ka + j * 4;
        float4 v = (kg < K) ? *(const float4*)&A[arow + kg]
                            : make_float4(0.f, 0.f, 0.f, 0.f);
        raf[j * 4 + 0] = v.x; raf[j * 4 + 1] = v.y;
        raf[j * 4 + 2] = v.z; raf[j * 4 + 3] = v.w;
      }
    } else {
      const int kg = k0 + ka;
      raf[0] = (kg < K) ? A[arow + kg] : 0.f;
      raf[1] = (kg + 1 < K) ? A[arow + kg + 1] : 0.f;
    }
  };

  auto loadB = [&](int c) {
    const int k0 = c << 5;
#pragma unroll
    for (int j = 0; j < 8; j++) {
      const int kg = k0 + kb0 + j;       // wave-uniform
      float v = 0.f;
      if (MODE == 2) {
        if (kg < K && pp < N)
          v = (kg < C1) ? B1[(long)kg * N + pp] : B2[(long)(kg - C1) * N + pp];
      } else if (MODE == 4) {
        if (kg < K) {
          int ci = kg >> lgT;                      // scalar decode
          int tt = kg & ((1 << lgT) - 1);
          int tx = tt & ((1 << lgnx) - 1);
          int r_ = tt >> lgnx;
          int ty = r_ & ((1 << lgny) - 1);
          int tz = r_ >> lgny;
          long base = (long)ci * vin + (long)tz * Din * Din + ty * Din + tx;
          if ((vmask >> tt) & 1) v = B1[base + laneOff];
        }
      } else { // MODE 0 / 3
        if (kg < K) {
          int ci = kg / 27;                        // scalar decode (uniform)
          int tap = kg - ci * 27;
          int kz = tap / 9;
          int r9 = tap - kz * 9;
          int ky = r9 / 3;
          int kx = r9 - ky * 3;
          long base = (long)ci * vin + (long)kz * Din * Din + ky * Din + kx;
          if ((vmask >> tap) & 1) v = B1[base + laneOff];
        }
      }
      rb[j] = v;
    }
  };

  if (c0 < c1) { loadA(c0); loadB(c0); }

  for (int c = c0; c < c1; ++c) {
    __syncthreads();
#pragma unroll
    for (int j = 0; j < AEL; j++) At[ka + j][co_a] = raf[j];
#pragma unroll
    for (int j = 0; j < 8; j++) Bt[kb0 + j][pb] = rb[j];
    if (c + 1 < c1) { loadA(c + 1); loadB(c + 1); }
    __syncthreads();
#pragma unroll
    for (int kk = 0; kk < 32; ++kk) {
      const float4 b4 = *(const float4*)&Bt[kk][p0];
      if (MR == 4) {
        const float4 a4 = *(const float4*)&At[kk][co0];
        acc[0][0] += a4.x * b4.x; acc[0][1] += a4.x * b4.y;
        acc[0][2] += a4.x * b4.z; acc[0][3] += a4.x * b4.w;
        acc[1][0] += a4.y * b4.x; acc[1][1] += a4.y * b4.y;
        acc[1][2] += a4.y * b4.z; acc[1][3] += a4.y * b4.w;
        acc[2][0] += a4.z * b4.x; acc[2][1] += a4.z * b4.y;
        acc[2][2] += a4.z * b4.z; acc[2][3] += a4.z * b4.w;
        acc[3][0] += a4.w * b4.x; acc[3][1] += a4.w * b4.y;
        acc[3][2] += a4.w * b4.z; acc[3][3] += a4.w * b4.w;
      } else {
        const float a = At[kk][co0];
        acc[0][0] += a * b4.x; acc[0][1] += a * b4.y;
        acc[0][2] += a * b4.z; acc[0][3] += a * b4.w;
      }
    }
  }

  if (MODE == 4 && gridDim.z == 1) {
    const int lgD = 31 - __clz(Dout);
    const int DF = Din << 1;
    const long voxF = (long)DF * DF * DF;
#pragma unroll
    for (int mr = 0; mr < MR; mr++) {
#pragma unroll
      for (int e = 0; e < 4; e++) {
        int pp2 = n0 + p0 + e;
        if (pp2 < N) {
          int ox = pp2 & (Dout - 1), oy = (pp2 >> lgD) & (Dout - 1),
              oz = pp2 >> (2 * lgD);
          long fc = ((long)(2 * oz + pz) * DF + (2 * oy + py)) * DF +
                    (2 * ox + px);
          C[(long)(m0 + co0 + mr) * voxF + fc] = acc[mr][e];
        }
      }
    }
  } else {
    float* Cz = C + (long)blockIdx.z * ((long)M * N);
#pragma unroll
    for (int mr = 0; mr < MR; mr++) {
      if (n0 + p0 < N) {
        float4 v = make_float4(acc[mr][0], acc[mr][1], acc[mr][2], acc[mr][3]);
        *(float4*)&Cz[(long)(m0 + co0 + mr) * N + n0 + p0] = v;
      }
    }
  }
}

// ================= hierarchical masked BN stats =================
__global__ __launch_bounds__(TPB) void k_stats1(const float* __restrict__ a,
                                                const float* __restrict__ m,
                                                float* __restrict__ part,
                                                float* __restrict__ partM,
                                                int vox, int chunk) {
  const int s = blockIdx.x, c = blockIdx.y;
  const float* ap = a + (long)c * vox + (long)s * chunk;
  const float* mp = m + (long)s * chunk;
  float s0 = 0.f, s1 = 0.f, sm = 0.f;
  for (int i = threadIdx.x; i < chunk; i += TPB) {
    float mv = mp[i];
    float v = ap[i] * mv;
    s0 += v; s1 += v * v; sm += mv;
  }
  __shared__ float sh0[TPB], sh1[TPB], sh2[TPB];
  sh0[threadIdx.x] = s0; sh1[threadIdx.x] = s1; sh2[threadIdx.x] = sm;
  __syncthreads();
  for (int off = TPB / 2; off > 0; off >>= 1) {
    if (threadIdx.x < off) {
      sh0[threadIdx.x] += sh0[threadIdx.x + off];
      sh1[threadIdx.x] += sh1[threadIdx.x + off];
      sh2[threadIdx.x] += sh2[threadIdx.x + off];
    }
    __syncthreads();
  }
  if (threadIdx.x == 0) {
    const int S = gridDim.x;
    part[(c * S + s) * 2] = sh0[0];
    part[(c * S + s) * 2 + 1] = sh1[0];
    if (c == 0) partM[s] = sh2[0];
  }
}

// fused stats-finalize + BN + ReLU + mask (in-place)
__global__ __launch_bounds__(TPB) void k_apply(float* __restrict__ a,
                                               const float* __restrict__ m,
                                               const float* __restrict__ part,
                                               const float* __restrict__ partM,
                                               int S, int vox, long total) {
  long idx = blockIdx.x * (long)TPB + threadIdx.x;
  float mu, rs;
  if (vox >= TPB) {   // block lies within one channel (vox % 256 == 0)
    __shared__ float sst[2];
    int c = (int)((blockIdx.x * (long)TPB) / vox);
    if (threadIdx.x == 0) {
      float s0 = 0.f, s1 = 0.f, sm = 0.f;
      for (int s = 0; s < S; s++) {
        s0 += part[(c * S + s) * 2];
        s1 += part[(c * S + s) * 2 + 1];
        sm += partM[s];
      }
      float n = fmaxf(sm, 1.f);
      float mu_ = s0 / n;
      float var = fmaxf(s1 / n - mu_ * mu_, 0.f);
      sst[0] = mu_; sst[1] = rsqrtf(var + 1e-5f);
    }
    __syncthreads();
    mu = sst[0]; rs = sst[1];
    if (idx >= total) return;
  } else {            // vox < 256 -> S == 1, per-thread finalize (3 loads)
    if (idx >= total) return;
    int c = (int)(idx / vox);
    float s0 = part[c * 2], s1 = part[c * 2 + 1], sm = partM[0];
    float n = fmaxf(sm, 1.f);
    mu = s0 / n;
    float var = fmaxf(s1 / n - mu * mu, 0.f);
    rs = rsqrtf(var + 1e-5f);
  }
  int p = (int)(idx % vox);
  float v = (a[idx] - mu) * rs;
  a[idx] = fmaxf(v, 0.f) * m[p];
}

// same, but writes f32 output buffer (final layer)
__global__ __launch_bounds__(TPB) void k_apply_out(const float* __restrict__ a,
                                                   const float* __restrict__ m,
                                                   const float* __restrict__ part,
                                                   const float* __restrict__ partM,
                                                   float* __restrict__ out,
                                                   int S, int vox, long total) {
  long idx = blockIdx.x * (long)TPB + threadIdx.x;
  __shared__ float sst[2];
  int c = (int)((blockIdx.x * (long)TPB) / vox);
  if (threadIdx.x == 0) {
    float s0 = 0.f, s1 = 0.f, sm = 0.f;
    for (int s = 0; s < S; s++) {
      s0 += part[(c * S + s) * 2];
      s1 += part[(c * S + s) * 2 + 1];
      sm += partM[s];
    }
    float n = fmaxf(sm, 1.f);
    float mu_ = s0 / n;
    float var = fmaxf(s1 / n - mu_ * mu_, 0.f);
    sst[0] = mu_; sst[1] = rsqrtf(var + 1e-5f);
  }
  __syncthreads();
  if (idx >= total) return;
  float mu = sst[0], rs = sst[1];
  int p = (int)(idx % vox);
  float v = (a[idx] - mu) * rs;
  out[idx] = fmaxf(v, 0.f) * m[p];
}

// ================= workspace layout (floats) =================
constexpr long o_m0 = 0;          // 64^3
constexpr long o_m1 = 262144;     // 32^3
constexpr long o_m2 = 294912;     // 16^3
constexpr long o_m3 = 299008;     // 8^3
constexpr long o_m4 = 299520;     // 4^3
constexpr long o_m5 = 299584;     // 2^3
constexpr long o_st = 299592;     // (unused now)
constexpr long o_A  = 301696;     // 2M: xm -> split-K scratch -> u3 -> final preact
constexpr long o_B  = 2398848;    // 2M: a0 (feats0)
constexpr long o_C  = 4496000;    // 512K: a1 (feats1)
constexpr long o_D  = 5020288;    // 128K: a2 (feats2)
constexpr long o_E  = 5151360;    // 32K: a3 (feats3)
constexpr long o_F  = 5184128;    // 8K: a4
constexpr long o_G  = 5192320;    // 8K: a5
constexpr long o_H  = 5200512;    // 32K: u0
constexpr long o_I  = 5233280;    // 32K: f0
constexpr long o_J  = 5266048;    // 128K: u1
constexpr long o_K  = 5397120;    // 128K: f1
constexpr long o_L  = 5528192;    // 512K: u2
constexpr long o_M  = 6052480;    // 512K: f2
constexpr long o_N  = 6576768;    // 2M: f3 (dead until fu3 -> up3 scratch)
constexpr long o_P  = 8673920;    // 16K: BN partials
constexpr long o_PM = 8690304;    // 64: mask-count partials
constexpr long o_fin = o_A;       // 4M: final preact overlays A+B (both dead)

extern "C" void kernel_launch(void* const* d_in, const int* in_sizes, int n_in,
                              void* d_out, int out_size, void* d_ws, size_t ws_size,
                              hipStream_t stream) {
  const float* x      = (const float*)d_in[0];
  const float* mask   = (const float*)d_in[1];
  const float* w_enc0 = (const float*)d_in[2];
  const float* w_enc1 = (const float*)d_in[3];
  const float* w_enc2 = (const float*)d_in[4];
  const float* w_enc3 = (const float*)d_in[5];
  const float* w_btd  = (const float*)d_in[6];
  const float* w_btc  = (const float*)d_in[7];
  const float* w_up0  = (const float*)d_in[8];
  const float* w_fu0  = (const float*)d_in[9];
  const float* w_up1  = (const float*)d_in[10];
  const float* w_fu1  = (const float*)d_in[11];
  const float* w_up2  = (const float*)d_in[12];
  const float* w_fu2  = (const float*)d_in[13];
  const float* w_up3  = (const float*)d_in[14];
  const float* w_fu3  = (const float*)d_in[15];
  const float* w_fin  = (const float*)d_in[16];

  float* ws = (float*)d_ws;
  float* out = (float*)d_out;

  auto blocks = [](long n) { return (unsigned)((n + TPB - 1) / TPB); };

  // masks
  k_mask0<<<blocks(262144), TPB, 0, stream>>>(mask, ws + o_m0, 262144);
  k_downmask<<<blocks(32768), TPB, 0, stream>>>(ws + o_m0, ws + o_m1, 32);
  k_downmask<<<blocks(4096), TPB, 0, stream>>>(ws + o_m1, ws + o_m2, 16);
  k_downmask<<<blocks(512), TPB, 0, stream>>>(ws + o_m2, ws + o_m3, 8);
  k_downmask<<<blocks(64), TPB, 0, stream>>>(ws + o_m3, ws + o_m4, 4);
  k_downmask<<<blocks(8), TPB, 0, stream>>>(ws + o_m4, ws + o_m5, 2);

  // masked input -> A
  k_maskx<<<blocks(8L * 262144), TPB, 0, stream>>>(x, ws + o_m0, ws + o_A,
                                                   8L * 262144, 262144);

  auto bnrelu = [&](float* a, const float* m, int C, int vox) {
    int S = vox / TPB; if (S < 1) S = 1; if (S > 64) S = 64;
    int chunk = vox / S;
    dim3 g(S, C);
    k_stats1<<<g, TPB, 0, stream>>>(a, m, ws + o_P, ws + o_PM, vox, chunk);
    long total = (long)C * vox;
    k_apply<<<blocks(total), TPB, 0, stream>>>(a, m, ws + o_P, ws + o_PM, S,
                                               vox, total);
  };

#define GEMM(MT, MODE, A_, B1_, B2_, O_, M_, N_, K_, DIN_, DOUT_, C1_, Z_)   \
  do {                                                                        \
    int nch_ = ((K_) + 31) >> 5;                                              \
    int kper_ = (nch_ + (Z_) - 1) / (Z_);                                     \
    dim3 g_(((N_) + 63) / 64, (M_) / (MT), (Z_));                             \
    float* dst_ = ((Z_) > 1) ? (ws + o_A) : (O_);                             \
    k_gemm<MT, MODE><<<g_, TPB, 0, stream>>>(A_, B1_, B2_, dst_, M_, N_, K_,  \
                                             DIN_, DOUT_, C1_, kper_);        \
    if ((Z_) > 1)                                                             \
      k_sumparts<<<blocks((long)(M_) * (N_)), TPB, 0, stream>>>(              \
          ws + o_A, O_, (long)(M_) * (N_), (Z_));                             \
  } while (0)

  // parity-decomposed convT: 8 classes, each a dense shift-only GEMM
  auto convTpar = [&](const float* w, const float* in, float* o, int M, int Cin,
                      int Dh, float* scr, long scrCap) {
    int lgDh = 31 - __builtin_clz(Dh);
    int Np = Dh * Dh * Dh;
    for (int cls = 0; cls < 8; ++cls) {
      int px = cls & 1, py = (cls >> 1) & 1, pz = (cls >> 2) & 1;
      int T = 1 << ((1 - px) + (1 - py) + (1 - pz));
      int K = Cin * T;
      int nch = (K + 31) >> 5;
      long cap = scrCap / ((long)M * Np);
      int Z = nch; if (Z > cap) Z = (int)cap; if (Z > 128) Z = 128;
      if (Z < 1) Z = 1;
      int kper = (nch + Z - 1) / Z;
      dim3 g((Np + 63) / 64, M / 64, Z);
      if (Z == 1) {
        k_gemm<64, 4><<<g, TPB, 0, stream>>>(w, in, nullptr, o, M, Np, K,
                                             Dh, Dh, cls, kper);
      } else {
        k_gemm<64, 4><<<g, TPB, 0, stream>>>(w, in, nullptr, scr, M, Np, K,
                                             Dh, Dh, cls, kper);
        k_sumscat<<<blocks((long)M * Np), TPB, 0, stream>>>(scr, o, M, Np, Z,
                                                            Dh, lgDh, cls);
      }
    }
  };

  // ---------------- encoder ----------------
  GEMM(64, 0, w_enc0, ws + o_A, nullptr, ws + o_B, 64, 32768, 8 * 27, 64, 32, 0, 1);
  bnrelu(ws + o_B, ws + o_m1, 64, 32768);
  GEMM(64, 0, w_enc1, ws + o_B, nullptr, ws + o_C, 128, 4096, 64 * 27, 32, 16, 0, 4);
  bnrelu(ws + o_C, ws + o_m2, 128, 4096);
  GEMM(64, 0, w_enc2, ws + o_C, nullptr, ws + o_D, 256, 512, 128 * 27, 16, 8, 0, 16);
  bnrelu(ws + o_D, ws + o_m3, 256, 512);
  GEMM(64, 0, w_enc3, ws + o_D, nullptr, ws + o_E, 512, 64, 256 * 27, 8, 4, 0, 64);
  bnrelu(ws + o_E, ws + o_m4, 512, 64);

  // ---------------- bottleneck ----------------
  GEMM(64, 0, w_btd, ws + o_E, nullptr, ws + o_F, 1024, 8, 512 * 27, 4, 2, 0, 108);
  bnrelu(ws + o_F, ws + o_m5, 1024, 8);
  GEMM(64, 3, w_btc, ws + o_F, nullptr, ws + o_G, 1024, 8, 1024 * 27, 2, 2, 0, 108);
  bnrelu(ws + o_G, ws + o_m5, 1024, 8);

  // ---------------- decoder ----------------
  convTpar(w_up0, ws + o_G, ws + o_H, 512, 1024, 2, ws + o_A, 2097152);
  bnrelu(ws + o_H, ws + o_m4, 512, 64);
  GEMM(64, 2, w_fu0, ws + o_H, ws + o_E, ws + o_I, 512, 64, 1024, 4, 4, 512, 32);
  bnrelu(ws + o_I, ws + o_m4, 512, 64);

  convTpar(w_up1, ws + o_I, ws + o_J, 256, 512, 4, ws + o_A, 2097152);
  bnrelu(ws + o_J, ws + o_m3, 256, 512);
  GEMM(64, 2, w_fu1, ws + o_J, ws + o_D, ws + o_K, 256, 512, 512, 8, 8, 256, 16);
  bnrelu(ws + o_K, ws + o_m3, 256, 512);

  convTpar(w_up2, ws + o_K, ws + o_L, 128, 256, 8, ws + o_A, 2097152);
  bnrelu(ws + o_L, ws + o_m2, 128, 4096);
  GEMM(64, 2, w_fu2, ws + o_L, ws + o_C, ws + o_M, 128, 4096, 256, 16, 16, 128, 2);
  bnrelu(ws + o_M, ws + o_m2, 128, 4096);

  // up3 writes o_A; scratch = o_N (f3 not yet written -> dead here)
  convTpar(w_up3, ws + o_M, ws + o_A, 64, 128, 16, ws + o_N, 2097152);
  bnrelu(ws + o_A, ws + o_m1, 64, 32768);
  GEMM(64, 2, w_fu3, ws + o_A, ws + o_B, ws + o_N, 64, 32768, 128, 32, 32, 64, 1);
  bnrelu(ws + o_N, ws + o_m1, 64, 32768);

  // ---------------- final up (M=16): 8 parity classes, Z=1 direct ----------------
  for (int cls = 0; cls < 8; ++cls) {
    int px = cls & 1, py = (cls >> 1) & 1, pz = (cls >> 2) & 1;
    int T = 1 << ((1 - px) + (1 - py) + (1 - pz));
    int K = 64 * T;
    int nch = (K + 31) >> 5;
    dim3 g((32768 + 63) / 64, 1, 1);
    k_gemm<16, 4><<<g, TPB, 0, stream>>>(w_fin, ws + o_N, nullptr, ws + o_fin,
                                         16, 32768, K, 32, 32, cls, nch);
  }
  {
    int vox = 262144, C = 16;
    int S = 64, chunk = vox / S;
    dim3 g(S, C);
    k_stats1<<<g, TPB, 0, stream>>>(ws + o_fin, ws + o_m0, ws + o_P, ws + o_PM,
                                    vox, chunk);
    long total = (long)C * vox;
    k_apply_out<<<blocks(total), TPB, 0, stream>>>(ws + o_fin, ws + o_m0,
                                                   ws + o_P, ws + o_PM, out, S,
                                                   vox, total);
  }
#undef GEMM
}